// Round 14
// baseline (401.322 us; speedup 1.0000x reference)
//
#include <hip/hip_runtime.h>
#include <math.h>

typedef __bf16 bf16;
typedef __bf16 bf16x8 __attribute__((ext_vector_type(8)));
typedef __bf16 bf16x4v __attribute__((ext_vector_type(4)));
typedef float f32x4 __attribute__((ext_vector_type(4)));

#define NB 4
#define NT 2048
#define NC 2048
#define NH 16
#define ND 128
#define NROW (NB*NT)   // 8192

#define GLD16(g, l) __builtin_amdgcn_global_load_lds( \
    (__attribute__((address_space(1))) void*)(g), \
    (__attribute__((address_space(3))) void*)(l), 16, 0, 0)

// ---------------- prep: x->bf16 + omega (blocks 0..8191)  |  weights->bf16 (blocks 8192..24575) ----
__global__ void prep_kernel(const float* __restrict__ x, bf16* __restrict__ xb,
                            const float* __restrict__ w_om, const float* __restrict__ b_om,
                            float* __restrict__ omega,
                            const float* __restrict__ W0, const float* __restrict__ W1,
                            const float* __restrict__ W2, const float* __restrict__ W3,
                            bf16* __restrict__ o0, bf16* __restrict__ o1,
                            bf16* __restrict__ o2, bf16* __restrict__ o3) {
  int b = blockIdx.x;
  if (b < NROW) {
    const float4* xr = reinterpret_cast<const float4*>(x + (size_t)b * NC);
    const float4* wr = reinterpret_cast<const float4*>(w_om);
    bf16x4v* ob = reinterpret_cast<bf16x4v*>(xb + (size_t)b * NC);
    float sum = 0.f;
    for (int i = threadIdx.x; i < NC/4; i += 256) {
      float4 a = xr[i], bb = wr[i];
      sum += a.x*bb.x + a.y*bb.y + a.z*bb.z + a.w*bb.w;
      bf16x4v o;
      o[0] = (bf16)a.x; o[1] = (bf16)a.y; o[2] = (bf16)a.z; o[3] = (bf16)a.w;
      ob[i] = o;
    }
    for (int m = 32; m; m >>= 1) sum += __shfl_xor(sum, m);
    __shared__ float wsum[4];
    if ((threadIdx.x & 63) == 0) wsum[threadIdx.x >> 6] = sum;
    __syncthreads();
    if (threadIdx.x == 0) {
      float d = wsum[0] + wsum[1] + wsum[2] + wsum[3] + b_om[0];
      omega[b] = 1.f / (1.f + expf(-d * (1.f/16.f)));
    }
  } else {
    int i2 = b - NROW;
    int which = i2 >> 12;
    const float* in = which == 0 ? W0 : which == 1 ? W1 : which == 2 ? W2 : W3;
    bf16* out = which == 0 ? o0 : which == 1 ? o1 : which == 2 ? o2 : o3;
    int i = (i2 & 4095) * 256 + threadIdx.x;
    float4 v = reinterpret_cast<const float4*>(in)[i];
    bf16x4v o;
    o[0] = (bf16)v.x; o[1] = (bf16)v.y; o[2] = (bf16)v.z; o[3] = (bf16)v.w;
    reinterpret_cast<bf16x4v*>(out)[i] = o;
  }
}

// ---------------- exclusive cumsum over T per batch (fp64 accumulation) ----------------
__global__ void scan_kernel(const float* __restrict__ omega, float* __restrict__ phi) {
  int b = blockIdx.x;
  const float* om = omega + (size_t)b * NT;
  float* ph = phi + (size_t)b * NT;
  int t = threadIdx.x;
  float v[8]; float s = 0.f;
  #pragma unroll
  for (int j = 0; j < 8; j++) { v[j] = om[t*8 + j]; s += v[j]; }
  __shared__ float totals[256];
  __shared__ double base_sh[256];
  totals[t] = s;
  __syncthreads();
  if (t == 0) {
    double run = 0.0;
    for (int i = 0; i < 256; i++) { base_sh[i] = run; run += (double)totals[i]; }
  }
  __syncthreads();
  double run = base_sh[t];
  #pragma unroll
  for (int j = 0; j < 8; j++) { ph[t*8 + j] = (float)run; run += (double)v[j]; }
}

// ---------------- cos/sin table: [row][dd], dd in 0..63 ----------------
__global__ void sincos_kernel(const float* __restrict__ phi, const float* __restrict__ log_freq,
                              float* __restrict__ cos_t, float* __restrict__ sin_t) {
  int i = blockIdx.x * 256 + threadIdx.x;
  int row = i >> 6, dd = i & 63;
  float f = expf(log_freq[dd]);
  float a = phi[row] * f;
  float si, co;
  sincosf(a, &si, &co);
  cos_t[i] = co;
  sin_t[i] = si;
}

// ===== shared GEMM main-loop macros (8-phase counted-vmcnt + A-M0 reg cache + m201 BAR2) =====
#define GEMM_LOOP_DECLS \
  __shared__ bf16 Als[2][256 * 64]; \
  __shared__ bf16 Bls[2][256 * 64]; \
  const int t = threadIdx.x; \
  const int lane = t & 63, lg = lane >> 4, l15 = lane & 15; \
  const int wid = t >> 6, wm = wid >> 1, wn = wid & 1; \
  const int wg = (bid & 7) * 32 + (bid >> 3); \
  const int m0 = (wg >> 3) * 256, n0 = (wg & 7) * 256; \
  const size_t K2 = (size_t)NC * 2; \
  const int u = t >> 3; \
  const int scol = ((t & 7) * 16) ^ ((u & 7) << 4); \
  const char* a1S = (const char*)Ag + (size_t)(m0 + (u >> 5) * 64 + (u & 31)) * K2 + scol; \
  const char* b1S = (const char*)Bg + (size_t)(n0 + u) * K2 + scol; \
  const int colk0 = (lg * 16) ^ ((l15 & 7) << 4); \
  const int colk1 = colk0 ^ 64; \
  char* const A0u1 = (char*)&Als[0][0]; \
  char* const A0u2 = A0u1 + 16384; \
  char* const A1u1 = (char*)&Als[1][0]; \
  char* const A1u2 = A1u1 + 16384; \
  char* const B0u1 = (char*)&Bls[0][0]; \
  char* const B0u2 = B0u1 + 16384; \
  char* const B1u1 = (char*)&Bls[1][0]; \
  char* const B1u2 = B1u1 + 16384; \
  f32x4 acc[4][8] = {}; \
  bf16x8 aC[2][2], aM0[2][2], bC[4][2];

#define STG(src, dst, kt) do { \
    const char* s_ = (src) + (size_t)(kt) * 128; \
    char* d_ = (dst) + t * 16; \
    GLD16(s_, d_); GLD16(s_ + (size_t)128 * K2, d_ + 8192); } while(0)
#define STG_A1(kt, d) STG(a1S, (d) ? A1u1 : A0u1, kt)
#define STG_A2(kt, d) STG(a1S + (size_t)32 * K2, (d) ? A1u2 : A0u2, kt)
#define STG_B1(kt, d) STG(b1S, (d) ? B1u1 : B0u1, kt)
#define STG_B2(kt, d) STG(b1S + (size_t)64 * K2, (d) ? B1u2 : B0u2, kt)

#define RDA(base) do { _Pragma("unroll") \
    for (int i2 = 0; i2 < 2; i2++) { \
      const char* p_ = (base) + (wm * 32 + i2 * 16 + l15) * 128; \
      aC[i2][0] = *(const bf16x8*)(p_ + colk0); \
      aC[i2][1] = *(const bf16x8*)(p_ + colk1); } } while(0)
#define RDAM(base) do { _Pragma("unroll") \
    for (int i2 = 0; i2 < 2; i2++) { \
      const char* p_ = (base) + (wm * 32 + i2 * 16 + l15) * 128; \
      aM0[i2][0] = *(const bf16x8*)(p_ + colk0); \
      aM0[i2][1] = *(const bf16x8*)(p_ + colk1); } } while(0)
#define RDB(base) do { _Pragma("unroll") \
    for (int j2 = 0; j2 < 4; j2++) { \
      const char* p_ = (base) + (wn * 64 + j2 * 16 + l15) * 128; \
      bC[j2][0] = *(const bf16x8*)(p_ + colk0); \
      bC[j2][1] = *(const bf16x8*)(p_ + colk1); } } while(0)

#define MMX(AF, IB, JB) do { __builtin_amdgcn_s_setprio(1); \
    _Pragma("unroll") \
    for (int kk = 0; kk < 2; kk++) \
      _Pragma("unroll") \
      for (int i2 = 0; i2 < 2; i2++) \
        _Pragma("unroll") \
        for (int j2 = 0; j2 < 4; j2++) \
          acc[(IB)+i2][(JB)+j2] = __builtin_amdgcn_mfma_f32_16x16x32_bf16(AF[i2][kk], bC[j2][kk], acc[(IB)+i2][(JB)+j2], 0,0,0); \
    __builtin_amdgcn_s_setprio(0); } while(0)
#define MM(IB, JB)  MMX(aC, IB, JB)
#define MM0(IB, JB) MMX(aM0, IB, JB)

#define VM(n) asm volatile("s_waitcnt vmcnt(" #n ")" ::: "memory")
#define BAR() do { __builtin_amdgcn_s_barrier(); asm volatile("" ::: "memory"); } while(0)
#define LGK() asm volatile("s_waitcnt lgkmcnt(0)" ::: "memory")

// m201-faithful: each phase ends with a second barrier after the MFMA cluster.
#define GEMM_MAIN_LOOP \
  STG_A1(0, 0); STG_A2(0, 0); STG_B1(0, 0); STG_B2(0, 0); STG_B1(1, 1); STG_A2(1, 1); \
  VM(6); BAR(); \
  _Pragma("unroll 1") \
  for (int i = 0; i < 15; i++) { \
    const int o1 = 2*i + 1, e2 = 2*i + 2, o3 = 2*i + 3; \
    RDAM(A0u1); RDB(B0u1);          BAR(); STG_A1(o1, 1); LGK(); MM0(0, 0); BAR(); \
    RDA(A0u2); VM(6);               BAR(); STG_B2(o1, 1); LGK(); MM(2, 0);  BAR(); \
    RDB(B0u2);                      BAR(); STG_B1(e2, 0); LGK(); MM(2, 4);  BAR(); \
    VM(4);                          BAR(); STG_A2(e2, 0);        MM0(0, 4); BAR(); \
    RDAM(A1u1); RDB(B1u1);          BAR(); STG_A1(e2, 0); LGK(); MM0(0, 0); BAR(); \
    RDA(A1u2); VM(6);               BAR(); STG_B2(e2, 0); LGK(); MM(2, 0);  BAR(); \
    RDB(B1u2);                      BAR(); STG_B1(o3, 1); LGK(); MM(2, 4);  BAR(); \
    VM(4);                          BAR(); STG_A2(o3, 1);        MM0(0, 4); BAR(); \
  } \
  { \
    RDAM(A0u1); RDB(B0u1);          BAR(); STG_A1(31, 1); LGK(); MM0(0, 0); BAR(); \
    RDA(A0u2); VM(6);               BAR(); STG_B2(31, 1); LGK(); MM(2, 0);  BAR(); \
    RDB(B0u2);                      BAR();                LGK(); MM(2, 4);  BAR(); \
    VM(2);                          BAR();                       MM0(0, 4); BAR(); \
    RDAM(A1u1); RDB(B1u1);          BAR();                LGK(); MM0(0, 0); BAR(); \
    RDA(A1u2); VM(0);               BAR();                LGK(); MM(2, 0);  BAR(); \
    RDB(B1u2);                      BAR();                LGK(); MM(2, 4);  BAR(); \
                                    BAR();                       MM0(0, 4); \
  }

// ---------------- fused q/k/v projection: 768 blocks, which = bid>>8 ----------------
__global__ __launch_bounds__(512, 2)
void gemm_qkv(const bf16* __restrict__ Ag,
              const bf16* __restrict__ Wq, const bf16* __restrict__ Wk, const bf16* __restrict__ Wv,
              bf16* __restrict__ qo, bf16* __restrict__ ko, bf16* __restrict__ vto,
              const float* __restrict__ cos_t, const float* __restrict__ sin_t,
              const float* __restrict__ q_gamma, const float* __restrict__ k_gamma) {
  const int bid3 = blockIdx.x;
  const int which = bid3 >> 8;
  const int bid = bid3 & 255;
  const bf16* Bg = which == 0 ? Wq : which == 1 ? Wk : Wv;

  GEMM_LOOP_DECLS
  GEMM_MAIN_LOOP

  if (which < 2) {
    // rotate + rmsnorm epilogue
    const float* gamma = which ? k_gamma : q_gamma;
    const float outscale = which ? 1.0f : 0.12751726f;   // log2(e)/sqrt(128) folded into q
    bf16* out = which ? ko : qo;
    #pragma unroll
    for (int mi = 0; mi < 4; mi++) {
      #pragma unroll
      for (int r = 0; r < 4; r++) {
        int m = m0 + wm*64 + mi*16 + lg*4 + r;
        float ss = 0.f;
        #pragma unroll
        for (int nj = 0; nj < 8; nj++) { float v = acc[mi][nj][r]; ss += v*v; }
        ss += __shfl_xor(ss, 1); ss += __shfl_xor(ss, 2);
        ss += __shfl_xor(ss, 4); ss += __shfl_xor(ss, 8);
        float scale = rsqrtf(ss * (1.f/128.f) + 1e-5f) * outscale;
        size_t rowb = (size_t)m * NC + n0 + wn*128;
        size_t tabb = (size_t)m * 64;
        #pragma unroll
        for (int nj = 0; nj < 4; nj++) {
          int dd = nj*16 + l15;
          float c = cos_t[tabb + dd];
          float s = sin_t[tabb + dd];
          float t1 = acc[mi][nj][r], t2 = acc[mi][nj+4][r];
          float o1 = (t1*c + t2*s) * scale * gamma[dd];
          float o2 = (t2*c - t1*s) * scale * gamma[dd + 64];
          out[rowb + dd] = (bf16)o1;
          out[rowb + dd + 64] = (bf16)o2;
        }
      }
    }
  } else {
    // transposed V write: Vt[b][h][d][t], packed 4-t bf16x4 stores
    const int h = (n0 + wn*128) >> 7;
    #pragma unroll
    for (int mi = 0; mi < 4; mi++) {
      int m_base = m0 + wm*64 + mi*16 + lg*4;   // 4 consecutive t in acc[mi][*][0..3]
      int bidx = m_base >> 11, tt = m_base & (NT-1);
      size_t hb = (((size_t)bidx * NH + h) * ND) * NT + tt;
      #pragma unroll
      for (int nj = 0; nj < 8; nj++) {
        int d = nj*16 + l15;
        f32x4 v = acc[mi][nj];
        bf16x4v o;
        o[0] = (bf16)v[0]; o[1] = (bf16)v[1]; o[2] = (bf16)v[2]; o[3] = (bf16)v[3];
        *reinterpret_cast<bf16x4v*>(&vto[hb + (size_t)d * NT]) = o;
      }
    }
  }
}

// ---------------- output projection: fp32 out ----------------
__global__ __launch_bounds__(512, 2)
void gemm_out(const bf16* __restrict__ Ag, const bf16* __restrict__ Bg, float* __restrict__ out) {
  const int bid = blockIdx.x;

  GEMM_LOOP_DECLS
  GEMM_MAIN_LOOP

  #pragma unroll
  for (int mi = 0; mi < 4; mi++) {
    #pragma unroll
    for (int r = 0; r < 4; r++) {
      int m = m0 + wm*64 + mi*16 + lg*4 + r;
      size_t rowb = (size_t)m * NC + n0 + wn*128;
      #pragma unroll
      for (int nj = 0; nj < 8; nj++)
        out[rowb + nj*16 + l15] = acc[mi][nj][r];
    }
  }
}

#undef GEMM_LOOP_DECLS
#undef GEMM_MAIN_LOOP
#undef STG
#undef STG_A1
#undef STG_A2
#undef STG_B1
#undef STG_B2
#undef RDA
#undef RDAM
#undef RDB
#undef MMX
#undef MM
#undef MM0
#undef VM
#undef BAR
#undef LGK

// ---------------- causal flash attention v7 (round-11 best, unchanged) ----------------
__global__ __launch_bounds__(512, 2)
void fa_kernel(const bf16* __restrict__ Qg, const bf16* __restrict__ Kg,
               const bf16* __restrict__ Vt, bf16* __restrict__ Og) {
  __shared__ bf16 Kls[2][64 * 128];
  __shared__ bf16 Vls[2][128 * 64];
  __shared__ bf16 Pls[8][32 * 64];
  const int t = threadIdx.x, w = t >> 6, lane = t & 63, lg = lane >> 4, l15 = lane & 15;
  const int bh = blockIdx.x;
  const int qb = (gridDim.y - 1) - blockIdx.y;   // big blocks dispatch first
  const size_t qkbase = (size_t)(bh >> 4) * NT * NC + (size_t)(bh & 15) * ND;
  const size_t vbase  = (size_t)bh * ND * NT;
  const int q0 = qb * 256 + w * 32;

  bf16x8 qf[2][4];
  #pragma unroll
  for (int mt = 0; mt < 2; mt++)
    #pragma unroll
    for (int kc = 0; kc < 4; kc++)
      qf[mt][kc] = *reinterpret_cast<const bf16x8*>(
          Qg + qkbase + (size_t)(q0 + mt*16 + l15) * NC + kc*32 + lg*8);

  f32x4 oacc[2][8] = {};
  f32x4 lacc[2] = {};
  float m_run[2][4];
  #pragma unroll
  for (int mt = 0; mt < 2; mt++)
    #pragma unroll
    for (int r = 0; r < 4; r++) m_run[mt][r] = -1e30f;

  bf16x8 vone;
  #pragma unroll
  for (int i = 0; i < 8; i++) vone[i] = (bf16)1.0f;

  const int kinS = ((t & 15) * 16) ^ (((t >> 4) & 7) << 4);
  const char* ksrc0 = (const char*)(Kg + qkbase) + (size_t)(t >> 4) * (NC*2) + kinS;
  const int vinS = ((t & 7) * 16) ^ (((t >> 3) & 7) << 4);
  const char* vsrc0 = (const char*)(Vt + vbase) + (size_t)(t >> 3) * (NT*2) + vinS;

#define STAGE_KV(kt, dd) do { \
    const char* ks_ = ksrc0 + (size_t)(kt) * 64 * (NC*2); \
    const char* vs_ = vsrc0 + (size_t)(kt) * 128; \
    char* kd_ = (char*)&Kls[dd][0] + t * 16; \
    char* vd_ = (char*)&Vls[dd][0] + t * 16; \
    GLD16(ks_,                        kd_); \
    GLD16(ks_ + (size_t)32 * NC * 2,  kd_ + 8192); \
    GLD16(vs_,                        vd_); \
    GLD16(vs_ + (size_t)64 * NT * 2,  vd_ + 8192); \
  } while(0)

  const int ntiles = 4 * qb + 4;
  STAGE_KV(0, 0);
  asm volatile("s_waitcnt vmcnt(0)" ::: "memory");
  __builtin_amdgcn_s_barrier();
  asm volatile("" ::: "memory");

  for (int kt = 0; kt < ntiles; kt++) {
    const int d = kt & 1;
    const int kv0 = kt * 64;
    if (kt + 1 < ntiles) STAGE_KV(kt + 1, d ^ 1);

    if (q0 + 31 >= kv0) {
      f32x4 s[2][4] = {};
      __builtin_amdgcn_s_setprio(1);
      #pragma unroll
      for (int kc = 0; kc < 4; kc++) {
        bf16x8 kf[4];
        const int swz = ((kc*64 + lg*16) ^ ((l15 & 7) << 4));
        #pragma unroll
        for (int nt = 0; nt < 4; nt++)
          kf[nt] = *reinterpret_cast<const bf16x8*>((const char*)&Kls[d][0] + (nt*16 + l15) * 256 + swz);
        #pragma unroll
        for (int mt = 0; mt < 2; mt++)
          #pragma unroll
          for (int nt = 0; nt < 4; nt++)
            s[mt][nt] = __builtin_amdgcn_mfma_f32_16x16x32_bf16(qf[mt][kc], kf[nt], s[mt][nt], 0, 0, 0);
      }
      __builtin_amdgcn_s_setprio(0);

      if (kv0 + 63 > q0) {
        #pragma unroll
        for (int mt = 0; mt < 2; mt++)
          #pragma unroll
          for (int nt = 0; nt < 4; nt++) {
            int kv = kv0 + nt*16 + l15;
            #pragma unroll
            for (int r = 0; r < 4; r++)
              if (kv > q0 + mt*16 + lg*4 + r) s[mt][nt][r] = -1e30f;
          }
      }

      // fast threshold test (no cross-lane reduce on the common path)
      int exceed = 0;
      #pragma unroll
      for (int mt = 0; mt < 2; mt++)
        #pragma unroll
        for (int r = 0; r < 4; r++) {
          float thr = m_run[mt][r] + 8.0f;
          exceed |= (s[mt][0][r] > thr) | (s[mt][1][r] > thr)
                  | (s[mt][2][r] > thr) | (s[mt][3][r] > thr);
        }
      if (__any(exceed)) {
        float tmax[2][4];
        #pragma unroll
        for (int mt = 0; mt < 2; mt++)
          #pragma unroll
          for (int r = 0; r < 4; r++) {
            float tm = fmaxf(fmaxf(s[mt][0][r], s[mt][1][r]), fmaxf(s[mt][2][r], s[mt][3][r]));
            tm = fmaxf(tm, __shfl_xor(tm, 1));
            tm = fmaxf(tm, __shfl_xor(tm, 2));
            tm = fmaxf(tm, __shfl_xor(tm, 4));
            tm = fmaxf(tm, __shfl_xor(tm, 8));
            tmax[mt][r] = tm;
          }
        #pragma unroll
        for (int mt = 0; mt < 2; mt++) {
          f32x4 alv;
          #pragma unroll
          for (int r = 0; r < 4; r++) {
            float mn = fmaxf(m_run[mt][r], tmax[mt][r]);
            alv[r] = exp2f(m_run[mt][r] - mn);
            m_run[mt][r] = mn;
          }
          #pragma unroll
          for (int dt = 0; dt < 8; dt++) {
            f32x4 o = oacc[mt][dt];
            o[0] *= alv[0]; o[1] *= alv[1]; o[2] *= alv[2]; o[3] *= alv[3];
            oacc[mt][dt] = o;
          }
          f32x4 lv = lacc[mt];
          lv[0] *= alv[0]; lv[1] *= alv[1]; lv[2] *= alv[2]; lv[3] *= alv[3];
          lacc[mt] = lv;
        }
      }

      char* pw = (char*)&Pls[w][0];
      #pragma unroll
      for (int mt = 0; mt < 2; mt++)
        #pragma unroll
        for (int r = 0; r < 4; r++) {
          float p0 = exp2f(s[mt][0][r] - m_run[mt][r]);
          float p1 = exp2f(s[mt][1][r] - m_run[mt][r]);
          float p2 = exp2f(s[mt][2][r] - m_run[mt][r]);
          float p3 = exp2f(s[mt][3][r] - m_run[mt][r]);
          int qrow = mt*16 + lg*4 + r;
          int rb = qrow * 128, cX = (qrow & 7) << 4;
          *(bf16*)(pw + rb + ((       2*l15) ^ cX)) = (bf16)p0;
          *(bf16*)(pw + rb + (( 32 +  2*l15) ^ cX)) = (bf16)p1;
          *(bf16*)(pw + rb + (( 64 +  2*l15) ^ cX)) = (bf16)p2;
          *(bf16*)(pw + rb + (( 96 +  2*l15) ^ cX)) = (bf16)p3;
        }

      asm volatile("s_waitcnt lgkmcnt(0)" ::: "memory");

      bf16x8 pf[2][2];
      #pragma unroll
      for (int mt = 0; mt < 2; mt++)
        #pragma unroll
        for (int kc2 = 0; kc2 < 2; kc2++)
          pf[mt][kc2] = *reinterpret_cast<const bf16x8*>(
              pw + (mt*16 + l15) * 128 + ((kc2*64 + lg*16) ^ ((l15 & 7) << 4)));
      __builtin_amdgcn_s_setprio(1);
      #pragma unroll
      for (int kc2 = 0; kc2 < 2; kc2++) {
        #pragma unroll
        for (int mt = 0; mt < 2; mt++)
          lacc[mt] = __builtin_amdgcn_mfma_f32_16x16x32_bf16(pf[mt][kc2], vone, lacc[mt], 0, 0, 0);
        const int swz = ((kc2*64 + lg*16) ^ ((l15 & 7) << 4));
        #pragma unroll
        for (int dt = 0; dt < 8; dt++) {
          bf16x8 vf = *reinterpret_cast<const bf16x8*>((const char*)&Vls[d][0] + (dt*16 + l15) * 128 + swz);
          #pragma unroll
          for (int mt = 0; mt < 2; mt++)
            oacc[mt][dt] = __builtin_amdgcn_mfma_f32_16x16x32_bf16(pf[mt][kc2], vf, oacc[mt][dt], 0, 0, 0);
        }
      }
      __builtin_amdgcn_s_setprio(0);
    }

    asm volatile("s_waitcnt vmcnt(0)" ::: "memory");
    __builtin_amdgcn_s_barrier();
    asm volatile("" ::: "memory");
  }
#undef STAGE_KV

  #pragma unroll
  for (int mt = 0; mt < 2; mt++)
    #pragma unroll
    for (int r = 0; r < 4; r++) {
      float inv = 1.f / lacc[mt][r];
      size_t orow = qkbase + (size_t)(q0 + mt*16 + lg*4 + r) * NC;
      #pragma unroll
      for (int dt = 0; dt < 8; dt++)
        Og[orow + dt*16 + l15] = (bf16)(oacc[mt][dt][r] * inv);
    }
}

// ---------------- host launch ----------------
extern "C" void kernel_launch(void* const* d_in, const int* in_sizes, int n_in,
                              void* d_out, int out_size, void* d_ws, size_t ws_size,
                              hipStream_t stream) {
  (void)in_sizes; (void)n_in; (void)out_size; (void)ws_size;
  const float* x       = (const float*)d_in[0];
  const float* Wq      = (const float*)d_in[1];
  const float* Wk      = (const float*)d_in[2];
  const float* Wv      = (const float*)d_in[3];
  const float* Wo      = (const float*)d_in[4];
  const float* w_omega = (const float*)d_in[5];
  const float* b_omega = (const float*)d_in[6];
  const float* log_freq= (const float*)d_in[7];
  const float* q_gamma = (const float*)d_in[8];
  const float* k_gamma = (const float*)d_in[9];

  char* p = (char*)d_ws;
  auto alloc = [&](size_t bytes) { void* r = (void*)p; p += (bytes + 255) & ~(size_t)255; return r; };
  bf16* xb   = (bf16*)alloc((size_t)NROW * NC * 2);
  bf16* wqb  = (bf16*)alloc((size_t)NC * NC * 2);
  bf16* wkb  = (bf16*)alloc((size_t)NC * NC * 2);
  bf16* wvb  = (bf16*)alloc((size_t)NC * NC * 2);
  bf16* wob  = (bf16*)alloc((size_t)NC * NC * 2);
  bf16* qb   = (bf16*)alloc((size_t)NROW * NC * 2);
  bf16* kb   = (bf16*)alloc((size_t)NROW * NC * 2);
  bf16* vt   = (bf16*)alloc((size_t)NROW * NC * 2);
  bf16* ob   = (bf16*)alloc((size_t)NROW * NC * 2);
  float* omega = (float*)alloc((size_t)NROW * 4);
  float* phi   = (float*)alloc((size_t)NROW * 4);
  float* cos_t = (float*)alloc((size_t)NROW * 64 * 4);
  float* sin_t = (float*)alloc((size_t)NROW * 64 * 4);

  prep_kernel<<<NROW + 16384, 256, 0, stream>>>(x, xb, w_omega, b_omega, omega,
                                                Wq, Wk, Wv, Wo, wqb, wkb, wvb, wob);
  scan_kernel<<<NB, 256, 0, stream>>>(omega, phi);
  sincos_kernel<<<NROW * 64 / 256, 256, 0, stream>>>(phi, log_freq, cos_t, sin_t);

  gemm_qkv<<<768, 512, 0, stream>>>(xb, wqb, wkb, wvb, qb, kb, vt,
                                    cos_t, sin_t, q_gamma, k_gamma);

  fa_kernel<<<dim3(NB * NH, NT / 256), 512, 0, stream>>>(qb, kb, vt, ob);

  gemm_out<<<256, 512, 0, stream>>>(ob, wob, (float*)d_out);
}

// Round 15
// 392.377 us; speedup vs baseline: 1.0228x; 1.0228x over previous
//
#include <hip/hip_runtime.h>
#include <math.h>

typedef __bf16 bf16;
typedef __bf16 bf16x8 __attribute__((ext_vector_type(8)));
typedef __bf16 bf16x4v __attribute__((ext_vector_type(4)));
typedef float f32x4 __attribute__((ext_vector_type(4)));

#define NB 4
#define NT 2048
#define NC 2048
#define NH 16
#define ND 128
#define NROW (NB*NT)   // 8192

#define GLD16(g, l) __builtin_amdgcn_global_load_lds( \
    (__attribute__((address_space(1))) void*)(g), \
    (__attribute__((address_space(3))) void*)(l), 16, 0, 0)

// ---------------- prep: x->bf16 + omega (blocks 0..8191)  |  weights->bf16 (blocks 8192..24575) ----
__global__ void prep_kernel(const float* __restrict__ x, bf16* __restrict__ xb,
                            const float* __restrict__ w_om, const float* __restrict__ b_om,
                            float* __restrict__ omega,
                            const float* __restrict__ W0, const float* __restrict__ W1,
                            const float* __restrict__ W2, const float* __restrict__ W3,
                            bf16* __restrict__ o0, bf16* __restrict__ o1,
                            bf16* __restrict__ o2, bf16* __restrict__ o3) {
  int b = blockIdx.x;
  if (b < NROW) {
    const float4* xr = reinterpret_cast<const float4*>(x + (size_t)b * NC);
    const float4* wr = reinterpret_cast<const float4*>(w_om);
    bf16x4v* ob = reinterpret_cast<bf16x4v*>(xb + (size_t)b * NC);
    float sum = 0.f;
    for (int i = threadIdx.x; i < NC/4; i += 256) {
      float4 a = xr[i], bb = wr[i];
      sum += a.x*bb.x + a.y*bb.y + a.z*bb.z + a.w*bb.w;
      bf16x4v o;
      o[0] = (bf16)a.x; o[1] = (bf16)a.y; o[2] = (bf16)a.z; o[3] = (bf16)a.w;
      ob[i] = o;
    }
    for (int m = 32; m; m >>= 1) sum += __shfl_xor(sum, m);
    __shared__ float wsum[4];
    if ((threadIdx.x & 63) == 0) wsum[threadIdx.x >> 6] = sum;
    __syncthreads();
    if (threadIdx.x == 0) {
      float d = wsum[0] + wsum[1] + wsum[2] + wsum[3] + b_om[0];
      omega[b] = 1.f / (1.f + expf(-d * (1.f/16.f)));
    }
  } else {
    int i2 = b - NROW;
    int which = i2 >> 12;
    const float* in = which == 0 ? W0 : which == 1 ? W1 : which == 2 ? W2 : W3;
    bf16* out = which == 0 ? o0 : which == 1 ? o1 : which == 2 ? o2 : o3;
    int i = (i2 & 4095) * 256 + threadIdx.x;
    float4 v = reinterpret_cast<const float4*>(in)[i];
    bf16x4v o;
    o[0] = (bf16)v.x; o[1] = (bf16)v.y; o[2] = (bf16)v.z; o[3] = (bf16)v.w;
    reinterpret_cast<bf16x4v*>(out)[i] = o;
  }
}

// ---------------- exclusive cumsum over T per batch (fp64 accumulation) ----------------
__global__ void scan_kernel(const float* __restrict__ omega, float* __restrict__ phi) {
  int b = blockIdx.x;
  const float* om = omega + (size_t)b * NT;
  float* ph = phi + (size_t)b * NT;
  int t = threadIdx.x;
  float v[8]; float s = 0.f;
  #pragma unroll
  for (int j = 0; j < 8; j++) { v[j] = om[t*8 + j]; s += v[j]; }
  __shared__ float totals[256];
  __shared__ double base_sh[256];
  totals[t] = s;
  __syncthreads();
  if (t == 0) {
    double run = 0.0;
    for (int i = 0; i < 256; i++) { base_sh[i] = run; run += (double)totals[i]; }
  }
  __syncthreads();
  double run = base_sh[t];
  #pragma unroll
  for (int j = 0; j < 8; j++) { ph[t*8 + j] = (float)run; run += (double)v[j]; }
}

// ---------------- cos/sin table: [row][dd], dd in 0..63 ----------------
__global__ void sincos_kernel(const float* __restrict__ phi, const float* __restrict__ log_freq,
                              float* __restrict__ cos_t, float* __restrict__ sin_t) {
  int i = blockIdx.x * 256 + threadIdx.x;
  int row = i >> 6, dd = i & 63;
  float f = expf(log_freq[dd]);
  float a = phi[row] * f;
  float si, co;
  sincosf(a, &si, &co);
  cos_t[i] = co;
  sin_t[i] = si;
}

// ===== shared GEMM main-loop macros (8-phase counted-vmcnt + A-M0 reg cache; round-13 best) =====
#define GEMM_LOOP_DECLS \
  __shared__ bf16 Als[2][256 * 64]; \
  __shared__ bf16 Bls[2][256 * 64]; \
  const int t = threadIdx.x; \
  const int lane = t & 63, lg = lane >> 4, l15 = lane & 15; \
  const int wid = t >> 6, wm = wid >> 1, wn = wid & 1; \
  const int wg = (bid & 7) * 32 + (bid >> 3); \
  const int m0 = (wg >> 3) * 256, n0 = (wg & 7) * 256; \
  const size_t K2 = (size_t)NC * 2; \
  const int u = t >> 3; \
  const int scol = ((t & 7) * 16) ^ ((u & 7) << 4); \
  const char* a1S = (const char*)Ag + (size_t)(m0 + (u >> 5) * 64 + (u & 31)) * K2 + scol; \
  const char* b1S = (const char*)Bg + (size_t)(n0 + u) * K2 + scol; \
  const int colk0 = (lg * 16) ^ ((l15 & 7) << 4); \
  const int colk1 = colk0 ^ 64; \
  char* const A0u1 = (char*)&Als[0][0]; \
  char* const A0u2 = A0u1 + 16384; \
  char* const A1u1 = (char*)&Als[1][0]; \
  char* const A1u2 = A1u1 + 16384; \
  char* const B0u1 = (char*)&Bls[0][0]; \
  char* const B0u2 = B0u1 + 16384; \
  char* const B1u1 = (char*)&Bls[1][0]; \
  char* const B1u2 = B1u1 + 16384; \
  f32x4 acc[4][8] = {}; \
  bf16x8 aC[2][2], aM0[2][2], bC[4][2];

#define STG(src, dst, kt) do { \
    const char* s_ = (src) + (size_t)(kt) * 128; \
    char* d_ = (dst) + t * 16; \
    GLD16(s_, d_); GLD16(s_ + (size_t)128 * K2, d_ + 8192); } while(0)
#define STG_A1(kt, d) STG(a1S, (d) ? A1u1 : A0u1, kt)
#define STG_A2(kt, d) STG(a1S + (size_t)32 * K2, (d) ? A1u2 : A0u2, kt)
#define STG_B1(kt, d) STG(b1S, (d) ? B1u1 : B0u1, kt)
#define STG_B2(kt, d) STG(b1S + (size_t)64 * K2, (d) ? B1u2 : B0u2, kt)

#define RDA(base) do { _Pragma("unroll") \
    for (int i2 = 0; i2 < 2; i2++) { \
      const char* p_ = (base) + (wm * 32 + i2 * 16 + l15) * 128; \
      aC[i2][0] = *(const bf16x8*)(p_ + colk0); \
      aC[i2][1] = *(const bf16x8*)(p_ + colk1); } } while(0)
#define RDAM(base) do { _Pragma("unroll") \
    for (int i2 = 0; i2 < 2; i2++) { \
      const char* p_ = (base) + (wm * 32 + i2 * 16 + l15) * 128; \
      aM0[i2][0] = *(const bf16x8*)(p_ + colk0); \
      aM0[i2][1] = *(const bf16x8*)(p_ + colk1); } } while(0)
#define RDB(base) do { _Pragma("unroll") \
    for (int j2 = 0; j2 < 4; j2++) { \
      const char* p_ = (base) + (wn * 64 + j2 * 16 + l15) * 128; \
      bC[j2][0] = *(const bf16x8*)(p_ + colk0); \
      bC[j2][1] = *(const bf16x8*)(p_ + colk1); } } while(0)

#define MMX(AF, IB, JB) do { __builtin_amdgcn_s_setprio(1); \
    _Pragma("unroll") \
    for (int kk = 0; kk < 2; kk++) \
      _Pragma("unroll") \
      for (int i2 = 0; i2 < 2; i2++) \
        _Pragma("unroll") \
        for (int j2 = 0; j2 < 4; j2++) \
          acc[(IB)+i2][(JB)+j2] = __builtin_amdgcn_mfma_f32_16x16x32_bf16(AF[i2][kk], bC[j2][kk], acc[(IB)+i2][(JB)+j2], 0,0,0); \
    __builtin_amdgcn_s_setprio(0); } while(0)
#define MM(IB, JB)  MMX(aC, IB, JB)
#define MM0(IB, JB) MMX(aM0, IB, JB)

#define VM(n) asm volatile("s_waitcnt vmcnt(" #n ")" ::: "memory")
#define BAR() do { __builtin_amdgcn_s_barrier(); asm volatile("" ::: "memory"); } while(0)
#define LGK() asm volatile("s_waitcnt lgkmcnt(0)" ::: "memory")

#define GEMM_MAIN_LOOP \
  STG_A1(0, 0); STG_A2(0, 0); STG_B1(0, 0); STG_B2(0, 0); STG_B1(1, 1); STG_A2(1, 1); \
  VM(6); BAR(); \
  _Pragma("unroll 1") \
  for (int i = 0; i < 15; i++) { \
    const int o1 = 2*i + 1, e2 = 2*i + 2, o3 = 2*i + 3; \
    RDAM(A0u1); RDB(B0u1);          BAR(); STG_A1(o1, 1); LGK(); MM0(0, 0); \
    RDA(A0u2); VM(6);               BAR(); STG_B2(o1, 1); LGK(); MM(2, 0); \
    RDB(B0u2);                      BAR(); STG_B1(e2, 0); LGK(); MM(2, 4); \
    VM(4);                          BAR(); STG_A2(e2, 0);        MM0(0, 4); \
    RDAM(A1u1); RDB(B1u1);          BAR(); STG_A1(e2, 0); LGK(); MM0(0, 0); \
    RDA(A1u2); VM(6);               BAR(); STG_B2(e2, 0); LGK(); MM(2, 0); \
    RDB(B1u2);                      BAR(); STG_B1(o3, 1); LGK(); MM(2, 4); \
    VM(4);                          BAR(); STG_A2(o3, 1);        MM0(0, 4); \
  } \
  { \
    RDAM(A0u1); RDB(B0u1);          BAR(); STG_A1(31, 1); LGK(); MM0(0, 0); \
    RDA(A0u2); VM(6);               BAR(); STG_B2(31, 1); LGK(); MM(2, 0); \
    RDB(B0u2);                      BAR();                LGK(); MM(2, 4); \
    VM(2);                          BAR();                       MM0(0, 4); \
    RDAM(A1u1); RDB(B1u1);          BAR();                LGK(); MM0(0, 0); \
    RDA(A1u2); VM(0);               BAR();                LGK(); MM(2, 0); \
    RDB(B1u2);                      BAR();                LGK(); MM(2, 4); \
                                    BAR();                       MM0(0, 4); \
  }

// ---------------- fused q/k/v projection: 768 blocks, which = bid>>8 ----------------
__global__ __launch_bounds__(512, 2)
void gemm_qkv(const bf16* __restrict__ Ag,
              const bf16* __restrict__ Wq, const bf16* __restrict__ Wk, const bf16* __restrict__ Wv,
              bf16* __restrict__ qo, bf16* __restrict__ ko, bf16* __restrict__ vto,
              const float* __restrict__ cos_t, const float* __restrict__ sin_t,
              const float* __restrict__ q_gamma, const float* __restrict__ k_gamma) {
  const int bid3 = blockIdx.x;
  const int which = bid3 >> 8;
  const int bid = bid3 & 255;
  const bf16* Bg = which == 0 ? Wq : which == 1 ? Wk : Wv;

  GEMM_LOOP_DECLS
  GEMM_MAIN_LOOP

  if (which < 2) {
    // rotate + rmsnorm epilogue
    const float* gamma = which ? k_gamma : q_gamma;
    const float outscale = which ? 1.0f : 0.12751726f;   // log2(e)/sqrt(128) folded into q
    bf16* out = which ? ko : qo;
    #pragma unroll
    for (int mi = 0; mi < 4; mi++) {
      #pragma unroll
      for (int r = 0; r < 4; r++) {
        int m = m0 + wm*64 + mi*16 + lg*4 + r;
        float ss = 0.f;
        #pragma unroll
        for (int nj = 0; nj < 8; nj++) { float v = acc[mi][nj][r]; ss += v*v; }
        ss += __shfl_xor(ss, 1); ss += __shfl_xor(ss, 2);
        ss += __shfl_xor(ss, 4); ss += __shfl_xor(ss, 8);
        float scale = rsqrtf(ss * (1.f/128.f) + 1e-5f) * outscale;
        size_t rowb = (size_t)m * NC + n0 + wn*128;
        size_t tabb = (size_t)m * 64;
        #pragma unroll
        for (int nj = 0; nj < 4; nj++) {
          int dd = nj*16 + l15;
          float c = cos_t[tabb + dd];
          float s = sin_t[tabb + dd];
          float t1 = acc[mi][nj][r], t2 = acc[mi][nj+4][r];
          float o1 = (t1*c + t2*s) * scale * gamma[dd];
          float o2 = (t2*c - t1*s) * scale * gamma[dd + 64];
          out[rowb + dd] = (bf16)o1;
          out[rowb + dd + 64] = (bf16)o2;
        }
      }
    }
  } else {
    // transposed V write: Vt[b][h][d][t], packed 4-t bf16x4 stores
    const int h = (n0 + wn*128) >> 7;
    #pragma unroll
    for (int mi = 0; mi < 4; mi++) {
      int m_base = m0 + wm*64 + mi*16 + lg*4;   // 4 consecutive t in acc[mi][*][0..3]
      int bidx = m_base >> 11, tt = m_base & (NT-1);
      size_t hb = (((size_t)bidx * NH + h) * ND) * NT + tt;
      #pragma unroll
      for (int nj = 0; nj < 8; nj++) {
        int d = nj*16 + l15;
        f32x4 v = acc[mi][nj];
        bf16x4v o;
        o[0] = (bf16)v[0]; o[1] = (bf16)v[1]; o[2] = (bf16)v[2]; o[3] = (bf16)v[3];
        *reinterpret_cast<bf16x4v*>(&vto[hb + (size_t)d * NT]) = o;
      }
    }
  }
}

// ---------------- output projection: fp32 out ----------------
__global__ __launch_bounds__(512, 2)
void gemm_out(const bf16* __restrict__ Ag, const bf16* __restrict__ Bg, float* __restrict__ out) {
  const int bid = blockIdx.x;

  GEMM_LOOP_DECLS
  GEMM_MAIN_LOOP

  #pragma unroll
  for (int mi = 0; mi < 4; mi++) {
    #pragma unroll
    for (int r = 0; r < 4; r++) {
      int m = m0 + wm*64 + mi*16 + lg*4 + r;
      size_t rowb = (size_t)m * NC + n0 + wn*128;
      #pragma unroll
      for (int nj = 0; nj < 8; nj++)
        out[rowb + nj*16 + l15] = acc[mi][nj][r];
    }
  }
}

#undef GEMM_LOOP_DECLS
#undef GEMM_MAIN_LOOP
#undef STG
#undef STG_A1
#undef STG_A2
#undef STG_B1
#undef STG_B2
#undef RDA
#undef RDAM
#undef RDB
#undef MMX
#undef MM
#undef MM0
#undef VM
#undef BAR
#undef LGK

// ---------------- causal flash attention v7 (round-11 best, unchanged) ----------------
__global__ __launch_bounds__(512, 2)
void fa_kernel(const bf16* __restrict__ Qg, const bf16* __restrict__ Kg,
               const bf16* __restrict__ Vt, bf16* __restrict__ Og) {
  __shared__ bf16 Kls[2][64 * 128];
  __shared__ bf16 Vls[2][128 * 64];
  __shared__ bf16 Pls[8][32 * 64];
  const int t = threadIdx.x, w = t >> 6, lane = t & 63, lg = lane >> 4, l15 = lane & 15;
  const int bh = blockIdx.x;
  const int qb = (gridDim.y - 1) - blockIdx.y;   // big blocks dispatch first
  const size_t qkbase = (size_t)(bh >> 4) * NT * NC + (size_t)(bh & 15) * ND;
  const size_t vbase  = (size_t)bh * ND * NT;
  const int q0 = qb * 256 + w * 32;

  bf16x8 qf[2][4];
  #pragma unroll
  for (int mt = 0; mt < 2; mt++)
    #pragma unroll
    for (int kc = 0; kc < 4; kc++)
      qf[mt][kc] = *reinterpret_cast<const bf16x8*>(
          Qg + qkbase + (size_t)(q0 + mt*16 + l15) * NC + kc*32 + lg*8);

  f32x4 oacc[2][8] = {};
  f32x4 lacc[2] = {};
  float m_run[2][4];
  #pragma unroll
  for (int mt = 0; mt < 2; mt++)
    #pragma unroll
    for (int r = 0; r < 4; r++) m_run[mt][r] = -1e30f;

  bf16x8 vone;
  #pragma unroll
  for (int i = 0; i < 8; i++) vone[i] = (bf16)1.0f;

  const int kinS = ((t & 15) * 16) ^ (((t >> 4) & 7) << 4);
  const char* ksrc0 = (const char*)(Kg + qkbase) + (size_t)(t >> 4) * (NC*2) + kinS;
  const int vinS = ((t & 7) * 16) ^ (((t >> 3) & 7) << 4);
  const char* vsrc0 = (const char*)(Vt + vbase) + (size_t)(t >> 3) * (NT*2) + vinS;

#define STAGE_KV(kt, dd) do { \
    const char* ks_ = ksrc0 + (size_t)(kt) * 64 * (NC*2); \
    const char* vs_ = vsrc0 + (size_t)(kt) * 128; \
    char* kd_ = (char*)&Kls[dd][0] + t * 16; \
    char* vd_ = (char*)&Vls[dd][0] + t * 16; \
    GLD16(ks_,                        kd_); \
    GLD16(ks_ + (size_t)32 * NC * 2,  kd_ + 8192); \
    GLD16(vs_,                        vd_); \
    GLD16(vs_ + (size_t)64 * NT * 2,  vd_ + 8192); \
  } while(0)

  const int ntiles = 4 * qb + 4;
  STAGE_KV(0, 0);
  asm volatile("s_waitcnt vmcnt(0)" ::: "memory");
  __builtin_amdgcn_s_barrier();
  asm volatile("" ::: "memory");

  for (int kt = 0; kt < ntiles; kt++) {
    const int d = kt & 1;
    const int kv0 = kt * 64;
    if (kt + 1 < ntiles) STAGE_KV(kt + 1, d ^ 1);

    if (q0 + 31 >= kv0) {
      f32x4 s[2][4] = {};
      __builtin_amdgcn_s_setprio(1);
      #pragma unroll
      for (int kc = 0; kc < 4; kc++) {
        bf16x8 kf[4];
        const int swz = ((kc*64 + lg*16) ^ ((l15 & 7) << 4));
        #pragma unroll
        for (int nt = 0; nt < 4; nt++)
          kf[nt] = *reinterpret_cast<const bf16x8*>((const char*)&Kls[d][0] + (nt*16 + l15) * 256 + swz);
        #pragma unroll
        for (int mt = 0; mt < 2; mt++)
          #pragma unroll
          for (int nt = 0; nt < 4; nt++)
            s[mt][nt] = __builtin_amdgcn_mfma_f32_16x16x32_bf16(qf[mt][kc], kf[nt], s[mt][nt], 0, 0, 0);
      }
      __builtin_amdgcn_s_setprio(0);

      if (kv0 + 63 > q0) {
        #pragma unroll
        for (int mt = 0; mt < 2; mt++)
          #pragma unroll
          for (int nt = 0; nt < 4; nt++) {
            int kv = kv0 + nt*16 + l15;
            #pragma unroll
            for (int r = 0; r < 4; r++)
              if (kv > q0 + mt*16 + lg*4 + r) s[mt][nt][r] = -1e30f;
          }
      }

      // fast threshold test (no cross-lane reduce on the common path)
      int exceed = 0;
      #pragma unroll
      for (int mt = 0; mt < 2; mt++)
        #pragma unroll
        for (int r = 0; r < 4; r++) {
          float thr = m_run[mt][r] + 8.0f;
          exceed |= (s[mt][0][r] > thr) | (s[mt][1][r] > thr)
                  | (s[mt][2][r] > thr) | (s[mt][3][r] > thr);
        }
      if (__any(exceed)) {
        float tmax[2][4];
        #pragma unroll
        for (int mt = 0; mt < 2; mt++)
          #pragma unroll
          for (int r = 0; r < 4; r++) {
            float tm = fmaxf(fmaxf(s[mt][0][r], s[mt][1][r]), fmaxf(s[mt][2][r], s[mt][3][r]));
            tm = fmaxf(tm, __shfl_xor(tm, 1));
            tm = fmaxf(tm, __shfl_xor(tm, 2));
            tm = fmaxf(tm, __shfl_xor(tm, 4));
            tm = fmaxf(tm, __shfl_xor(tm, 8));
            tmax[mt][r] = tm;
          }
        #pragma unroll
        for (int mt = 0; mt < 2; mt++) {
          f32x4 alv;
          #pragma unroll
          for (int r = 0; r < 4; r++) {
            float mn = fmaxf(m_run[mt][r], tmax[mt][r]);
            alv[r] = exp2f(m_run[mt][r] - mn);
            m_run[mt][r] = mn;
          }
          #pragma unroll
          for (int dt = 0; dt < 8; dt++) {
            f32x4 o = oacc[mt][dt];
            o[0] *= alv[0]; o[1] *= alv[1]; o[2] *= alv[2]; o[3] *= alv[3];
            oacc[mt][dt] = o;
          }
          f32x4 lv = lacc[mt];
          lv[0] *= alv[0]; lv[1] *= alv[1]; lv[2] *= alv[2]; lv[3] *= alv[3];
          lacc[mt] = lv;
        }
      }

      char* pw = (char*)&Pls[w][0];
      #pragma unroll
      for (int mt = 0; mt < 2; mt++)
        #pragma unroll
        for (int r = 0; r < 4; r++) {
          float p0 = exp2f(s[mt][0][r] - m_run[mt][r]);
          float p1 = exp2f(s[mt][1][r] - m_run[mt][r]);
          float p2 = exp2f(s[mt][2][r] - m_run[mt][r]);
          float p3 = exp2f(s[mt][3][r] - m_run[mt][r]);
          int qrow = mt*16 + lg*4 + r;
          int rb = qrow * 128, cX = (qrow & 7) << 4;
          *(bf16*)(pw + rb + ((       2*l15) ^ cX)) = (bf16)p0;
          *(bf16*)(pw + rb + (( 32 +  2*l15) ^ cX)) = (bf16)p1;
          *(bf16*)(pw + rb + (( 64 +  2*l15) ^ cX)) = (bf16)p2;
          *(bf16*)(pw + rb + (( 96 +  2*l15) ^ cX)) = (bf16)p3;
        }

      asm volatile("s_waitcnt lgkmcnt(0)" ::: "memory");

      bf16x8 pf[2][2];
      #pragma unroll
      for (int mt = 0; mt < 2; mt++)
        #pragma unroll
        for (int kc2 = 0; kc2 < 2; kc2++)
          pf[mt][kc2] = *reinterpret_cast<const bf16x8*>(
              pw + (mt*16 + l15) * 128 + ((kc2*64 + lg*16) ^ ((l15 & 7) << 4)));
      __builtin_amdgcn_s_setprio(1);
      #pragma unroll
      for (int kc2 = 0; kc2 < 2; kc2++) {
        #pragma unroll
        for (int mt = 0; mt < 2; mt++)
          lacc[mt] = __builtin_amdgcn_mfma_f32_16x16x32_bf16(pf[mt][kc2], vone, lacc[mt], 0, 0, 0);
        const int swz = ((kc2*64 + lg*16) ^ ((l15 & 7) << 4));
        #pragma unroll
        for (int dt = 0; dt < 8; dt++) {
          bf16x8 vf = *reinterpret_cast<const bf16x8*>((const char*)&Vls[d][0] + (dt*16 + l15) * 128 + swz);
          #pragma unroll
          for (int mt = 0; mt < 2; mt++)
            oacc[mt][dt] = __builtin_amdgcn_mfma_f32_16x16x32_bf16(pf[mt][kc2], vf, oacc[mt][dt], 0, 0, 0);
        }
      }
      __builtin_amdgcn_s_setprio(0);
    }

    asm volatile("s_waitcnt vmcnt(0)" ::: "memory");
    __builtin_amdgcn_s_barrier();
    asm volatile("" ::: "memory");
  }
#undef STAGE_KV

  #pragma unroll
  for (int mt = 0; mt < 2; mt++)
    #pragma unroll
    for (int r = 0; r < 4; r++) {
      float inv = 1.f / lacc[mt][r];
      size_t orow = qkbase + (size_t)(q0 + mt*16 + lg*4 + r) * NC;
      #pragma unroll
      for (int dt = 0; dt < 8; dt++)
        Og[orow + dt*16 + l15] = (bf16)(oacc[mt][dt][r] * inv);
    }
}

// ---------------- host launch ----------------
extern "C" void kernel_launch(void* const* d_in, const int* in_sizes, int n_in,
                              void* d_out, int out_size, void* d_ws, size_t ws_size,
                              hipStream_t stream) {
  (void)in_sizes; (void)n_in; (void)out_size; (void)ws_size;
  const float* x       = (const float*)d_in[0];
  const float* Wq      = (const float*)d_in[1];
  const float* Wk      = (const float*)d_in[2];
  const float* Wv      = (const float*)d_in[3];
  const float* Wo      = (const float*)d_in[4];
  const float* w_omega = (const float*)d_in[5];
  const float* b_omega = (const float*)d_in[6];
  const float* log_freq= (const float*)d_in[7];
  const float* q_gamma = (const float*)d_in[8];
  const float* k_gamma = (const float*)d_in[9];

  char* p = (char*)d_ws;
  auto alloc = [&](size_t bytes) { void* r = (void*)p; p += (bytes + 255) & ~(size_t)255; return r; };
  bf16* xb   = (bf16*)alloc((size_t)NROW * NC * 2);
  bf16* wqb  = (bf16*)alloc((size_t)NC * NC * 2);
  bf16* wkb  = (bf16*)alloc((size_t)NC * NC * 2);
  bf16* wvb  = (bf16*)alloc((size_t)NC * NC * 2);
  bf16* wob  = (bf16*)alloc((size_t)NC * NC * 2);
  bf16* qb   = (bf16*)alloc((size_t)NROW * NC * 2);
  bf16* kb   = (bf16*)alloc((size_t)NROW * NC * 2);
  bf16* vt   = (bf16*)alloc((size_t)NROW * NC * 2);
  bf16* ob   = (bf16*)alloc((size_t)NROW * NC * 2);
  float* omega = (float*)alloc((size_t)NROW * 4);
  float* phi   = (float*)alloc((size_t)NROW * 4);
  float* cos_t = (float*)alloc((size_t)NROW * 64 * 4);
  float* sin_t = (float*)alloc((size_t)NROW * 64 * 4);

  prep_kernel<<<NROW + 16384, 256, 0, stream>>>(x, xb, w_omega, b_omega, omega,
                                                Wq, Wk, Wv, Wo, wqb, wkb, wvb, wob);
  scan_kernel<<<NB, 256, 0, stream>>>(omega, phi);
  sincos_kernel<<<NROW * 64 / 256, 256, 0, stream>>>(phi, log_freq, cos_t, sin_t);

  gemm_qkv<<<768, 512, 0, stream>>>(xb, wqb, wkb, wvb, qb, kb, vt,
                                    cos_t, sin_t, q_gamma, k_gamma);

  fa_kernel<<<dim3(NB * NH, NT / 256), 512, 0, stream>>>(qb, kb, vt, ob);

  gemm_out<<<256, 512, 0, stream>>>(ob, wob, (float*)d_out);
}